// Round 1
// baseline (1131.211 us; speedup 1.0000x reference)
//
#include <hip/hip_runtime.h>
#include <math.h>

// Problem constants (B=8, L=4096, D=512, H=8, top_k = int(log(4096)) = 8)
#define NB 8
#define NL 4096
#define ND 512
#define NK 8

// ---------------------------------------------------------------------------
// Small GEMM: C[i,j] = sum_{k<512} A[k*sa_k + i*sa_i] * B[k*sb_k + j*sb_j]
// Used for M = Wq^T Wk and Wov = Wo @ Wv. 512x512 output, naive (L2-resident).
// ---------------------------------------------------------------------------
__global__ void k_smallgemm(const float* __restrict__ A, const float* __restrict__ Bm,
                            float* __restrict__ C, int sa_k, int sa_i, int sb_k, int sb_j) {
    int i = blockIdx.y * 16 + threadIdx.y;
    int j = blockIdx.x * 16 + threadIdx.x;
    float acc = 0.f;
    for (int k = 0; k < ND; ++k)
        acc += A[k * sa_k + i * sa_i] * Bm[k * sb_k + j * sb_j];
    C[i * ND + j] = acc;
}

// bp[i] = bo[i] + sum_k Wo[i,k]*bv[k]
__global__ void k_biasprep(const float* __restrict__ Wo, const float* __restrict__ bv,
                           const float* __restrict__ bo, float* __restrict__ bp) {
    int i = blockIdx.x * blockDim.x + threadIdx.x;
    float acc = bo[i];
    for (int k = 0; k < ND; ++k) acc += Wo[i * ND + k] * bv[k];
    bp[i] = acc;
}

// ---------------------------------------------------------------------------
// Transpose X[b,l,c] -> XT[b,c,l]   (32x32 LDS tiles)
// ---------------------------------------------------------------------------
__global__ __launch_bounds__(256) void k_transpose(const float* __restrict__ X,
                                                   float* __restrict__ XT) {
    __shared__ float t[32][33];
    int b  = blockIdx.z;
    int l0 = blockIdx.x * 32;
    int c0 = blockIdx.y * 32;
    const float* Xb = X + (size_t)b * NL * ND;
    float* XTb = XT + (size_t)b * ND * NL;
    int tx = threadIdx.x, ty = threadIdx.y;  // 32 x 8
#pragma unroll
    for (int j = 0; j < 4; ++j)
        t[ty + j * 8][tx] = Xb[(size_t)(l0 + ty + j * 8) * ND + c0 + tx];
    __syncthreads();
#pragma unroll
    for (int j = 0; j < 4; ++j)
        XTb[(size_t)(c0 + ty + j * 8) * NL + l0 + tx] = t[tx][ty + j * 8];
}

// ---------------------------------------------------------------------------
// fp32 tiled GEMM core: C[row,n] = sum_k A[row,k]*Bm[n,k]  (both K-contiguous)
// BM=BN=64, BK=32, 256 threads, 4x4 micro-tile.
// Two epilogues: (a) write transposed YT[b, n, l]; (b) bias + normal layout.
// ---------------------------------------------------------------------------
#define GEMM_CORE(A_, B_)                                                        \
    __shared__ float smem[2 * 32 * 65];                                          \
    float* sA = smem;                                                            \
    float* sB = smem + 32 * 65;                                                  \
    const int tid = threadIdx.x;                                                 \
    const int l0 = blockIdx.x * 64;                                              \
    const int n0 = blockIdx.y * 64;                                              \
    const int tx = tid & 15, ty = tid >> 4;                                      \
    float acc[4][4] = {};                                                        \
    for (int k0 = 0; k0 < ND; k0 += 32) {                                        \
        _Pragma("unroll")                                                        \
        for (int v = 0; v < 2; ++v) {                                            \
            int vid = tid + v * 256;                                             \
            int row = vid >> 3;                                                  \
            int kc  = (vid & 7) * 4;                                             \
            float4 a4 = *(const float4*)(A_ + (size_t)(l0 + row) * ND + k0 + kc);\
            sA[(kc + 0) * 65 + row] = a4.x;                                      \
            sA[(kc + 1) * 65 + row] = a4.y;                                      \
            sA[(kc + 2) * 65 + row] = a4.z;                                      \
            sA[(kc + 3) * 65 + row] = a4.w;                                      \
            float4 b4 = *(const float4*)(B_ + (size_t)(n0 + row) * ND + k0 + kc);\
            sB[(kc + 0) * 65 + row] = b4.x;                                      \
            sB[(kc + 1) * 65 + row] = b4.y;                                      \
            sB[(kc + 2) * 65 + row] = b4.z;                                      \
            sB[(kc + 3) * 65 + row] = b4.w;                                      \
        }                                                                        \
        __syncthreads();                                                         \
        _Pragma("unroll 4")                                                      \
        for (int k = 0; k < 32; ++k) {                                           \
            float a_[4], b_[4];                                                  \
            _Pragma("unroll")                                                    \
            for (int i = 0; i < 4; ++i) a_[i] = sA[k * 65 + ty * 4 + i];         \
            _Pragma("unroll")                                                    \
            for (int j = 0; j < 4; ++j) b_[j] = sB[k * 65 + tx * 4 + j];         \
            _Pragma("unroll")                                                    \
            for (int i = 0; i < 4; ++i)                                          \
                _Pragma("unroll")                                                 \
                for (int j = 0; j < 4; ++j) acc[i][j] += a_[i] * b_[j];          \
        }                                                                        \
        __syncthreads();                                                         \
    }

// Y = X @ M^T, written transposed per batch: YT[b, j, l]
__global__ __launch_bounds__(256) void k_gemm_yt(const float* __restrict__ A,
                                                 const float* __restrict__ Bm,
                                                 float* __restrict__ YT) {
    GEMM_CORE(A, Bm)
    float* sT = smem;  // [64][65], reuse (fits exactly: 2*32*65 == 64*65)
#pragma unroll
    for (int i = 0; i < 4; ++i)
#pragma unroll
        for (int j = 0; j < 4; ++j)
            sT[(tx * 4 + j) * 65 + (ty * 4 + i)] = acc[i][j];
    __syncthreads();
#pragma unroll
    for (int r = 0; r < 16; ++r) {
        int idx = r * 256 + tid;
        int n = idx >> 6;
        int m = idx & 63;
        int rowg = l0 + m;
        int b = rowg >> 12;
        int lin = rowg & (NL - 1);
        YT[((size_t)b * ND + n0 + n) * NL + lin] = sT[n * 65 + m];
    }
}

// Out = Xagg @ Wov^T + bp, normal [row, col] layout
__global__ __launch_bounds__(256) void k_gemm_bias(const float* __restrict__ A,
                                                   const float* __restrict__ Bm,
                                                   const float* __restrict__ bp,
                                                   float* __restrict__ C) {
    GEMM_CORE(A, Bm)
#pragma unroll
    for (int i = 0; i < 4; ++i) {
        int row = l0 + ty * 4 + i;
        int col = n0 + tx * 4;
        float4 o;
        o.x = acc[i][0] + bp[col + 0];
        o.y = acc[i][1] + bp[col + 1];
        o.z = acc[i][2] + bp[col + 2];
        o.w = acc[i][3] + bp[col + 3];
        *(float4*)(C + (size_t)row * ND + col) = o;
    }
}

// ---------------------------------------------------------------------------
// 4096-pt complex FFT in LDS. DIT radix-2, input pre-bit-reversed, 256 thr.
// tw[k] = exp(sign*2*pi*i*k/4096), k < 2048.
// ---------------------------------------------------------------------------
__device__ __forceinline__ void fft4096_lds(float2* d, const float2* tw, int tid) {
    for (int s = 1; s <= 12; ++s) {
        int half = 1 << (s - 1);
        for (int q = tid; q < 2048; q += 256) {
            int grp = q >> (s - 1);
            int pos = q & (half - 1);
            int i1 = (grp << s) + pos;
            int i2 = i1 + half;
            float2 w = tw[pos << (12 - s)];
            float2 bb = d[i2];
            float tr = w.x * bb.x - w.y * bb.y;
            float ti = w.x * bb.y + w.y * bb.x;
            float2 aa = d[i1];
            d[i1] = make_float2(aa.x + tr, aa.y + ti);
            d[i2] = make_float2(aa.x - tr, aa.y - ti);
        }
        __syncthreads();
    }
}

__device__ __forceinline__ int brev12(int t) { return (int)(__brev((unsigned)t) >> 20); }

// Forward: per (batch, group of 8 channels): z = x + i*y, FFT, accumulate
// X_c(f)*conj(Y_c(f)) = Im(Z_f*Z_{-f})/2 + i*(|Z_f|^2-|Z_{-f}|^2)/4
// into registers; write partial[b, g, f] (float2).
__global__ __launch_bounds__(256) void k_fft_fwd(const float* __restrict__ XT,
                                                 const float* __restrict__ YT,
                                                 float2* __restrict__ partial) {
    __shared__ float2 data[4096];
    __shared__ float2 tw[2048];
    const int tid = threadIdx.x;
    const int b = blockIdx.x >> 6;
    const int g = blockIdx.x & 63;
    for (int k = tid; k < 2048; k += 256) {
        float sv, cv;
        sincosf(-6.283185307179586f * (float)k / 4096.0f, &sv, &cv);
        tw[k] = make_float2(cv, sv);
    }
    float2 acc[16];
#pragma unroll
    for (int r = 0; r < 16; ++r) acc[r] = make_float2(0.f, 0.f);
    for (int ch = 0; ch < 8; ++ch) {
        int c = g * 8 + ch;
        const float* xr = XT + ((size_t)b * ND + c) * NL;
        const float* yr = YT + ((size_t)b * ND + c) * NL;
        __syncthreads();  // protect data[] from previous iteration readers
        for (int t = tid; t < 4096; t += 256)
            data[brev12(t)] = make_float2(xr[t], yr[t]);
        __syncthreads();
        fft4096_lds(data, tw, tid);
#pragma unroll
        for (int r = 0; r < 16; ++r) {
            int f = r * 256 + tid;
            float2 A = data[f];
            float2 Bz = data[(4096 - f) & 4095];
            acc[r].x += 0.5f * (A.x * Bz.y + A.y * Bz.x);
            acc[r].y += 0.25f * ((A.x * A.x + A.y * A.y) - (Bz.x * Bz.x + Bz.y * Bz.y));
        }
    }
    float2* out = partial + ((size_t)b * 64 + g) * 4096;
#pragma unroll
    for (int r = 0; r < 16; ++r) out[r * 256 + tid] = acc[r];
}

// Inverse: reduce 64 partials -> Cf, IFFT, mean_corr = Re/ (N*D)
__global__ __launch_bounds__(256) void k_ifft(const float2* __restrict__ partial,
                                              float* __restrict__ mc) {
    __shared__ float2 data[4096];
    __shared__ float2 tw[2048];
    const int tid = threadIdx.x;
    const int b = blockIdx.x;
    for (int k = tid; k < 2048; k += 256) {
        float sv, cv;
        sincosf(6.283185307179586f * (float)k / 4096.0f, &sv, &cv);
        tw[k] = make_float2(cv, sv);
    }
    float2 acc[16];
#pragma unroll
    for (int r = 0; r < 16; ++r) acc[r] = make_float2(0.f, 0.f);
    for (int g = 0; g < 64; ++g) {
        const float2* p = partial + ((size_t)b * 64 + g) * 4096;
#pragma unroll
        for (int r = 0; r < 16; ++r) {
            float2 v = p[r * 256 + tid];
            acc[r].x += v.x;
            acc[r].y += v.y;
        }
    }
#pragma unroll
    for (int r = 0; r < 16; ++r) {
        int f = r * 256 + tid;
        data[brev12(f)] = acc[r];
    }
    __syncthreads();
    fft4096_lds(data, tw, tid);
    const float scale = 1.0f / (4096.0f * 512.0f);
    for (int t = tid; t < 4096; t += 256)
        mc[(size_t)b * NL + t] = data[t].x * scale;
}

// ---------------------------------------------------------------------------
// Top-8 + softmax per batch (repeated max; set-equality is what matters,
// weighted sum over i is permutation-invariant).
// ---------------------------------------------------------------------------
__global__ __launch_bounds__(256) void k_topk(const float* __restrict__ mc,
                                              float* __restrict__ wts,
                                              int* __restrict__ dly) {
    __shared__ float vals[4096];
    __shared__ float rv[256];
    __shared__ int ri[256];
    __shared__ float tv[NK];
    __shared__ int tix[NK];
    const int tid = threadIdx.x;
    const int b = blockIdx.x;
    for (int t = tid; t < 4096; t += 256) vals[t] = mc[(size_t)b * NL + t];
    __syncthreads();
    for (int it = 0; it < NK; ++it) {
        float bv = -3.0e38f;
        int bi = 0;
        for (int t = tid; t < 4096; t += 256) {
            float v = vals[t];
            if (v > bv) { bv = v; bi = t; }
        }
        rv[tid] = bv;
        ri[tid] = bi;
        __syncthreads();
        for (int off = 128; off > 0; off >>= 1) {
            if (tid < off) {
                if (rv[tid + off] > rv[tid]) {
                    rv[tid] = rv[tid + off];
                    ri[tid] = ri[tid + off];
                }
            }
            __syncthreads();
        }
        if (tid == 0) {
            tv[it] = rv[0];
            tix[it] = ri[0];
            vals[ri[0]] = -3.0e38f;
        }
        __syncthreads();
    }
    if (tid == 0) {
        float m = tv[0];  // repeated-max produces descending values
        float e[NK], s = 0.f;
        for (int i = 0; i < NK; ++i) { e[i] = expf(tv[i] - m); s += e[i]; }
        for (int i = 0; i < NK; ++i) {
            wts[b * NK + i] = e[i] / s;
            dly[b * NK + i] = tix[i];
        }
    }
}

// ---------------------------------------------------------------------------
// Xagg[b,l,:] = sum_i w[b,i] * X[b,(l+d_i)%L,:]   (float4 per thread)
// ---------------------------------------------------------------------------
__global__ __launch_bounds__(256) void k_gather(const float* __restrict__ X,
                                                const float* __restrict__ wts,
                                                const int* __restrict__ dly,
                                                float* __restrict__ Xagg) {
    __shared__ float sw[NK];
    __shared__ int sd[NK];
    int gid = blockIdx.x * 256 + threadIdx.x;  // float4 index; 4194304 total
    int b = gid >> 19;                         // 524288 float4 per batch
    int rem = gid & 524287;
    int l = rem >> 7;                          // 128 float4 per row
    int c4 = rem & 127;
    if (threadIdx.x < NK) {
        sw[threadIdx.x] = wts[b * NK + threadIdx.x];
        sd[threadIdx.x] = dly[b * NK + threadIdx.x];
    }
    __syncthreads();
    const float4* Xb = (const float4*)X + (size_t)b * 524288;
    float4 s = make_float4(0.f, 0.f, 0.f, 0.f);
#pragma unroll
    for (int i = 0; i < NK; ++i) {
        int ls = (l + sd[i]) & (NL - 1);
        float4 v = Xb[(size_t)ls * 128 + c4];
        float w = sw[i];
        s.x += w * v.x;
        s.y += w * v.y;
        s.z += w * v.z;
        s.w += w * v.w;
    }
    ((float4*)Xagg)[gid] = s;
}

// ---------------------------------------------------------------------------
extern "C" void kernel_launch(void* const* d_in, const int* in_sizes, int n_in,
                              void* d_out, int out_size, void* d_ws, size_t ws_size,
                              hipStream_t stream) {
    (void)in_sizes; (void)n_in; (void)out_size; (void)ws_size;
    const float* X  = (const float*)d_in[0];
    const float* Wq = (const float*)d_in[1];
    // bq = d_in[2] (zeros; bq/bk only enter via corr and vanish for zero bias)
    const float* Wk = (const float*)d_in[3];
    const float* Wv = (const float*)d_in[5];
    const float* bv = (const float*)d_in[6];
    const float* Wo = (const float*)d_in[7];
    const float* bo = (const float*)d_in[8];
    float* Out = (float*)d_out;

    char* ws = (char*)d_ws;
    const size_t MB = 1024 * 1024;
    float*  M       = (float*)(ws + 0 * MB);        // 1 MB
    float*  Wov     = (float*)(ws + 1 * MB);        // 1 MB
    float*  bp      = (float*)(ws + 2 * MB);        // 2 KB
    float*  XT      = (float*)(ws + 3 * MB);        // 64 MB; later reused as Xagg
    float*  YT      = (float*)(ws + 67 * MB);       // 64 MB
    float2* partial = (float2*)(ws + 131 * MB);     // 16.8 MB
    float*  mc      = (float*)(ws + 148 * MB);      // 128 KB
    float*  wts     = (float*)(ws + 149 * MB);      // 256 B
    int*    dly     = (int*)(ws + 149 * MB + 4096); // 256 B
    float*  Xagg    = XT;                           // XT dead after k_fft_fwd

    // 1) M = Wq^T Wk ;  Wov = Wo @ Wv ;  bp = Wo@bv + bo
    k_smallgemm<<<dim3(32, 32), dim3(16, 16), 0, stream>>>(Wq, Wk, M, ND, 1, ND, 1);
    k_smallgemm<<<dim3(32, 32), dim3(16, 16), 0, stream>>>(Wo, Wv, Wov, 1, ND, ND, 1);
    k_biasprep<<<1, 512, 0, stream>>>(Wo, bv, bo, bp);

    // 2) XT = transpose(X);  YT = (X @ M^T)^T per batch
    k_transpose<<<dim3(128, 16, NB), dim3(32, 8), 0, stream>>>(X, XT);
    k_gemm_yt<<<dim3(512, 8), 256, 0, stream>>>(X, M, YT);

    // 3) packed FFTs + channel-summed cross-spectrum partials; reduce + IFFT
    k_fft_fwd<<<512, 256, 0, stream>>>(XT, YT, partial);
    k_ifft<<<NB, 256, 0, stream>>>(partial, mc);

    // 4) top-8 delays + softmax weights per batch
    k_topk<<<NB, 256, 0, stream>>>(mc, wts, dly);

    // 5) weighted circular gather on X
    k_gather<<<16384, 256, 0, stream>>>(X, wts, dly, Xagg);

    // 6) Out = Xagg @ Wov^T + bp
    k_gemm_bias<<<dim3(512, 8), 256, 0, stream>>>(Xagg, Wov, bp, Out);
}

// Round 2
// 819.099 us; speedup vs baseline: 1.3810x; 1.3810x over previous
//
#include <hip/hip_runtime.h>
#include <math.h>

// Problem constants (B=8, L=4096, D=512, H=8, top_k = int(log(4096)) = 8)
#define NB 8
#define NL 4096
#define ND 512
#define NK 8

typedef unsigned short ushort_t;
typedef __bf16 bf16x8 __attribute__((ext_vector_type(8)));
typedef float f32x4 __attribute__((ext_vector_type(4)));

__device__ __forceinline__ unsigned short f2bf(float x) {
    unsigned u = __builtin_bit_cast(unsigned, x);
    u += 0x7fff + ((u >> 16) & 1);   // round-to-nearest-even
    return (unsigned short)(u >> 16);
}
__device__ __forceinline__ float bf2f(unsigned short b) {
    unsigned u = ((unsigned)b) << 16;
    return __builtin_bit_cast(float, u);
}

// ---------------------------------------------------------------------------
// Small GEMM: C[i,j] = sum_{k<512} A[k*sa_k + i*sa_i] * B[k*sb_k + j*sb_j]
// ---------------------------------------------------------------------------
__global__ void k_smallgemm(const float* __restrict__ A, const float* __restrict__ Bm,
                            float* __restrict__ C, int sa_k, int sa_i, int sb_k, int sb_j) {
    int i = blockIdx.y * 16 + threadIdx.y;
    int j = blockIdx.x * 16 + threadIdx.x;
    float acc = 0.f;
    for (int k = 0; k < ND; ++k)
        acc += A[k * sa_k + i * sa_i] * Bm[k * sb_k + j * sb_j];
    C[i * ND + j] = acc;
}

// bp[i] = bo[i] + sum_k Wo[i,k]*bv[k]
__global__ void k_biasprep(const float* __restrict__ Wo, const float* __restrict__ bv,
                           const float* __restrict__ bo, float* __restrict__ bp) {
    int i = blockIdx.x * blockDim.x + threadIdx.x;
    float acc = bo[i];
    for (int k = 0; k < ND; ++k) acc += Wo[i * ND + k] * bv[k];
    bp[i] = acc;
}

// Split a 512x512 fp32 matrix into Bs[row][0:512]=hi, Bs[row][512:1024]=lo (bf16)
__global__ __launch_bounds__(256) void k_splitB(const float* __restrict__ Msrc,
                                                ushort_t* __restrict__ Bs) {
    int gid = blockIdx.x * 256 + threadIdx.x;  // 512*128 float4 chunks
    int row = gid >> 7;
    int kc = (gid & 127) * 4;
    float4 v = *(const float4*)(Msrc + (size_t)row * ND + kc);
    ushort4 hi, lo;
    hi.x = f2bf(v.x); lo.x = f2bf(v.x - bf2f(hi.x));
    hi.y = f2bf(v.y); lo.y = f2bf(v.y - bf2f(hi.y));
    hi.z = f2bf(v.z); lo.z = f2bf(v.z - bf2f(hi.z));
    hi.w = f2bf(v.w); lo.w = f2bf(v.w - bf2f(hi.w));
    *(ushort4*)(Bs + (size_t)row * 1024 + kc) = hi;
    *(ushort4*)(Bs + (size_t)row * 1024 + 512 + kc) = lo;
}

// ---------------------------------------------------------------------------
// Transpose X[b,l,c] -> XT[b,c,l]   (32x32 LDS tiles)
// ---------------------------------------------------------------------------
__global__ __launch_bounds__(256) void k_transpose(const float* __restrict__ X,
                                                   float* __restrict__ XT) {
    __shared__ float t[32][33];
    int b  = blockIdx.z;
    int l0 = blockIdx.x * 32;
    int c0 = blockIdx.y * 32;
    const float* Xb = X + (size_t)b * NL * ND;
    float* XTb = XT + (size_t)b * ND * NL;
    int tx = threadIdx.x, ty = threadIdx.y;  // 32 x 8
#pragma unroll
    for (int j = 0; j < 4; ++j)
        t[ty + j * 8][tx] = Xb[(size_t)(l0 + ty + j * 8) * ND + c0 + tx];
    __syncthreads();
#pragma unroll
    for (int j = 0; j < 4; ++j)
        XTb[(size_t)(c0 + ty + j * 8) * NL + l0 + tx] = t[tx][ty + j * 8];
}

// ---------------------------------------------------------------------------
// Split-bf16 MFMA GEMM:  C[r,n] = sum_k A[r,k] * Brow[n,k]
// A fp32 [32768 x 512] converted to (hi,lo) on the fly into LDS.
// Bs bf16 [512 x 1024]: [n][0:512]=hi, [n][512:1024]=lo (pre-split).
// 3-term split: Ah*Bh + Ah*Bl + Al*Bh  (drops lo*lo, rel err ~1e-5).
// 128x128 C-tile, 256 thr = 4 waves (2x2), 4x4 16x16x32 MFMA frags per wave.
// EPI=0: write transposed YT[b,n,l]; EPI=1: bias + plain [r,n].
// ---------------------------------------------------------------------------
template <int EPI>
__global__ __launch_bounds__(256) void k_gemm_split(const float* __restrict__ A,
                                                    const ushort_t* __restrict__ Bs,
                                                    const float* __restrict__ bp,
                                                    float* __restrict__ Out) {
    __shared__ union USm {
        struct { ushort_t ahi[128 * 32]; ushort_t alo[128 * 32];
                 ushort_t bhi[128 * 32]; ushort_t blo[128 * 32]; } s;  // 32 KB
        float t[32 * 132];                                             // epilogue transpose
    } sm;
    const int tid = threadIdx.x;
    const int l0 = blockIdx.x * 128;
    const int n0 = blockIdx.y * 128;
    const int lane = tid & 63;
    const int w = tid >> 6;
    const int wr = (w & 1) * 64;
    const int wc = (w >> 1) * 64;
    const int m = lane & 15;
    const int quad = lane >> 4;

    const int arow = tid >> 3;        // A staging: 128 rows x 32 k fp32, float4 chunks
    const int akc = (tid & 7) * 4;
    const int brow = tid >> 2;        // B staging: 128 rows x 32 k bf16, 16B chunks
    const int bkc = (tid & 3) * 8;

    f32x4 acc[4][4];
#pragma unroll
    for (int i = 0; i < 4; ++i)
#pragma unroll
        for (int j = 0; j < 4; ++j) acc[i][j] = (f32x4){0.f, 0.f, 0.f, 0.f};

    for (int k0 = 0; k0 < ND; k0 += 32) {
        // --- B hi/lo tiles via async global->LDS (16B) ---
#pragma unroll
        for (int v = 0; v < 2; ++v) {
            int row = brow + v * 64;
            const ushort_t* ghi = Bs + (size_t)(n0 + row) * 1024 + k0 + bkc;
            __builtin_amdgcn_global_load_lds(
                (const __attribute__((address_space(1))) unsigned int*)ghi,
                (__attribute__((address_space(3))) unsigned int*)&sm.s.bhi[row * 32 + bkc],
                16, 0, 0);
            __builtin_amdgcn_global_load_lds(
                (const __attribute__((address_space(1))) unsigned int*)(ghi + 512),
                (__attribute__((address_space(3))) unsigned int*)&sm.s.blo[row * 32 + bkc],
                16, 0, 0);
        }
        // --- A tile: fp32 load -> split -> LDS ---
#pragma unroll
        for (int v = 0; v < 4; ++v) {
            int row = arow + v * 32;
            float4 a4 = *(const float4*)(A + (size_t)(l0 + row) * ND + k0 + akc);
            ushort4 hi, lo;
            hi.x = f2bf(a4.x); lo.x = f2bf(a4.x - bf2f(hi.x));
            hi.y = f2bf(a4.y); lo.y = f2bf(a4.y - bf2f(hi.y));
            hi.z = f2bf(a4.z); lo.z = f2bf(a4.z - bf2f(hi.z));
            hi.w = f2bf(a4.w); lo.w = f2bf(a4.w - bf2f(hi.w));
            *(ushort4*)&sm.s.ahi[row * 32 + akc] = hi;
            *(ushort4*)&sm.s.alo[row * 32 + akc] = lo;
        }
        __syncthreads();
        bf16x8 ah[4], al[4];
#pragma unroll
        for (int i = 0; i < 4; ++i) {
            ah[i] = *(const bf16x8*)&sm.s.ahi[(wr + 16 * i + m) * 32 + quad * 8];
            al[i] = *(const bf16x8*)&sm.s.alo[(wr + 16 * i + m) * 32 + quad * 8];
        }
#pragma unroll
        for (int j = 0; j < 4; ++j) {
            bf16x8 bh = *(const bf16x8*)&sm.s.bhi[(wc + 16 * j + m) * 32 + quad * 8];
            bf16x8 bl = *(const bf16x8*)&sm.s.blo[(wc + 16 * j + m) * 32 + quad * 8];
#pragma unroll
            for (int i = 0; i < 4; ++i) {
                acc[i][j] = __builtin_amdgcn_mfma_f32_16x16x32_bf16(ah[i], bh, acc[i][j], 0, 0, 0);
                acc[i][j] = __builtin_amdgcn_mfma_f32_16x16x32_bf16(ah[i], bl, acc[i][j], 0, 0, 0);
                acc[i][j] = __builtin_amdgcn_mfma_f32_16x16x32_bf16(al[i], bh, acc[i][j], 0, 0, 0);
            }
        }
        __syncthreads();
    }

    if (EPI == 1) {
        // bias + plain [row, col]
#pragma unroll
        for (int j = 0; j < 4; ++j) {
            int col = n0 + wc + 16 * j + m;
            float bv = bp[col];
#pragma unroll
            for (int i = 0; i < 4; ++i) {
                size_t rbase = (size_t)(l0 + wr + 16 * i + quad * 4) * ND + col;
#pragma unroll
                for (int r = 0; r < 4; ++r)
                    Out[rbase + (size_t)r * ND] = acc[i][j][r] + bv;
            }
        }
    } else {
        // transposed write YT[b, n, l] via LDS, 32-col chunks
#pragma unroll
        for (int c = 0; c < 4; ++c) {
            __syncthreads();
            if ((wc >> 6) == (c >> 1)) {
                int jb = (c & 1) * 2;
#pragma unroll
                for (int jj = 0; jj < 2; ++jj) {
                    int j = jb + jj;
                    int cl = 16 * jj + m;
#pragma unroll
                    for (int i = 0; i < 4; ++i)
#pragma unroll
                        for (int r = 0; r < 4; ++r)
                            sm.t[cl * 132 + wr + 16 * i + quad * 4 + r] = acc[i][j][r];
                }
            }
            __syncthreads();
#pragma unroll
            for (int it = 0; it < 16; ++it) {
                int idx = it * 256 + tid;
                int cl = idx >> 7;
                int row = idx & 127;
                int rg = l0 + row;
                Out[((size_t)((rg >> 12) * ND + n0 + c * 32 + cl)) * NL + (rg & 4095)] =
                    sm.t[cl * 132 + row];
            }
        }
    }
}

// ---------------------------------------------------------------------------
// 4096-pt complex FFT in LDS. DIT radix-2, input pre-bit-reversed, 256 thr.
// ---------------------------------------------------------------------------
__device__ __forceinline__ void fft4096_lds(float2* d, const float2* tw, int tid) {
    for (int s = 1; s <= 12; ++s) {
        int half = 1 << (s - 1);
        for (int q = tid; q < 2048; q += 256) {
            int grp = q >> (s - 1);
            int pos = q & (half - 1);
            int i1 = (grp << s) + pos;
            int i2 = i1 + half;
            float2 w = tw[pos << (12 - s)];
            float2 bb = d[i2];
            float tr = w.x * bb.x - w.y * bb.y;
            float ti = w.x * bb.y + w.y * bb.x;
            float2 aa = d[i1];
            d[i1] = make_float2(aa.x + tr, aa.y + ti);
            d[i2] = make_float2(aa.x - tr, aa.y - ti);
        }
        __syncthreads();
    }
}

__device__ __forceinline__ int brev12(int t) { return (int)(__brev((unsigned)t) >> 20); }

__global__ __launch_bounds__(256) void k_fft_fwd(const float* __restrict__ XT,
                                                 const float* __restrict__ YT,
                                                 float2* __restrict__ partial) {
    __shared__ float2 data[4096];
    __shared__ float2 tw[2048];
    const int tid = threadIdx.x;
    const int b = blockIdx.x >> 6;
    const int g = blockIdx.x & 63;
    for (int k = tid; k < 2048; k += 256) {
        float sv, cv;
        sincosf(-6.283185307179586f * (float)k / 4096.0f, &sv, &cv);
        tw[k] = make_float2(cv, sv);
    }
    float2 acc[16];
#pragma unroll
    for (int r = 0; r < 16; ++r) acc[r] = make_float2(0.f, 0.f);
    for (int ch = 0; ch < 8; ++ch) {
        int c = g * 8 + ch;
        const float* xr = XT + ((size_t)b * ND + c) * NL;
        const float* yr = YT + ((size_t)b * ND + c) * NL;
        __syncthreads();
        for (int t = tid; t < 4096; t += 256)
            data[brev12(t)] = make_float2(xr[t], yr[t]);
        __syncthreads();
        fft4096_lds(data, tw, tid);
#pragma unroll
        for (int r = 0; r < 16; ++r) {
            int f = r * 256 + tid;
            float2 A = data[f];
            float2 Bz = data[(4096 - f) & 4095];
            acc[r].x += 0.5f * (A.x * Bz.y + A.y * Bz.x);
            acc[r].y += 0.25f * ((A.x * A.x + A.y * A.y) - (Bz.x * Bz.x + Bz.y * Bz.y));
        }
    }
    float2* out = partial + ((size_t)b * 64 + g) * 4096;
#pragma unroll
    for (int r = 0; r < 16; ++r) out[r * 256 + tid] = acc[r];
}

__global__ __launch_bounds__(256) void k_ifft(const float2* __restrict__ partial,
                                              float* __restrict__ mc) {
    __shared__ float2 data[4096];
    __shared__ float2 tw[2048];
    const int tid = threadIdx.x;
    const int b = blockIdx.x;
    for (int k = tid; k < 2048; k += 256) {
        float sv, cv;
        sincosf(6.283185307179586f * (float)k / 4096.0f, &sv, &cv);
        tw[k] = make_float2(cv, sv);
    }
    float2 acc[16];
#pragma unroll
    for (int r = 0; r < 16; ++r) acc[r] = make_float2(0.f, 0.f);
    for (int g = 0; g < 64; ++g) {
        const float2* p = partial + ((size_t)b * 64 + g) * 4096;
#pragma unroll
        for (int r = 0; r < 16; ++r) {
            float2 v = p[r * 256 + tid];
            acc[r].x += v.x;
            acc[r].y += v.y;
        }
    }
#pragma unroll
    for (int r = 0; r < 16; ++r) {
        int f = r * 256 + tid;
        data[brev12(f)] = acc[r];
    }
    __syncthreads();
    fft4096_lds(data, tw, tid);
    const float scale = 1.0f / (4096.0f * 512.0f);
    for (int t = tid; t < 4096; t += 256)
        mc[(size_t)b * NL + t] = data[t].x * scale;
}

// ---------------------------------------------------------------------------
// Top-8 + softmax per batch
// ---------------------------------------------------------------------------
__global__ __launch_bounds__(256) void k_topk(const float* __restrict__ mc,
                                              float* __restrict__ wts,
                                              int* __restrict__ dly) {
    __shared__ float vals[4096];
    __shared__ float rv[256];
    __shared__ int ri[256];
    __shared__ float tv[NK];
    __shared__ int tix[NK];
    const int tid = threadIdx.x;
    const int b = blockIdx.x;
    for (int t = tid; t < 4096; t += 256) vals[t] = mc[(size_t)b * NL + t];
    __syncthreads();
    for (int it = 0; it < NK; ++it) {
        float bv = -3.0e38f;
        int bi = 0;
        for (int t = tid; t < 4096; t += 256) {
            float v = vals[t];
            if (v > bv) { bv = v; bi = t; }
        }
        rv[tid] = bv;
        ri[tid] = bi;
        __syncthreads();
        for (int off = 128; off > 0; off >>= 1) {
            if (tid < off) {
                if (rv[tid + off] > rv[tid]) {
                    rv[tid] = rv[tid + off];
                    ri[tid] = ri[tid + off];
                }
            }
            __syncthreads();
        }
        if (tid == 0) {
            tv[it] = rv[0];
            tix[it] = ri[0];
            vals[ri[0]] = -3.0e38f;
        }
        __syncthreads();
    }
    if (tid == 0) {
        float mx = tv[0];
        float e[NK], s = 0.f;
        for (int i = 0; i < NK; ++i) { e[i] = expf(tv[i] - mx); s += e[i]; }
        for (int i = 0; i < NK; ++i) {
            wts[b * NK + i] = e[i] / s;
            dly[b * NK + i] = tix[i];
        }
    }
}

// ---------------------------------------------------------------------------
// Xagg[b,l,:] = sum_i w[b,i] * X[b,(l+d_i)%L,:]   (float4 per thread)
// ---------------------------------------------------------------------------
__global__ __launch_bounds__(256) void k_gather(const float* __restrict__ X,
                                                const float* __restrict__ wts,
                                                const int* __restrict__ dly,
                                                float* __restrict__ Xagg) {
    __shared__ float sw[NK];
    __shared__ int sd[NK];
    int gid = blockIdx.x * 256 + threadIdx.x;
    int b = gid >> 19;
    int rem = gid & 524287;
    int l = rem >> 7;
    int c4 = rem & 127;
    if (threadIdx.x < NK) {
        sw[threadIdx.x] = wts[b * NK + threadIdx.x];
        sd[threadIdx.x] = dly[b * NK + threadIdx.x];
    }
    __syncthreads();
    const float4* Xb = (const float4*)X + (size_t)b * 524288;
    float4 s = make_float4(0.f, 0.f, 0.f, 0.f);
#pragma unroll
    for (int i = 0; i < NK; ++i) {
        int ls = (l + sd[i]) & (NL - 1);
        float4 v = Xb[(size_t)ls * 128 + c4];
        float w = sw[i];
        s.x += w * v.x;
        s.y += w * v.y;
        s.z += w * v.z;
        s.w += w * v.w;
    }
    ((float4*)Xagg)[gid] = s;
}

// ---------------------------------------------------------------------------
extern "C" void kernel_launch(void* const* d_in, const int* in_sizes, int n_in,
                              void* d_out, int out_size, void* d_ws, size_t ws_size,
                              hipStream_t stream) {
    (void)in_sizes; (void)n_in; (void)out_size; (void)ws_size;
    const float* X  = (const float*)d_in[0];
    const float* Wq = (const float*)d_in[1];
    const float* Wk = (const float*)d_in[3];
    const float* Wv = (const float*)d_in[5];
    const float* bv = (const float*)d_in[6];
    const float* Wo = (const float*)d_in[7];
    const float* bo = (const float*)d_in[8];
    float* Out = (float*)d_out;

    char* ws = (char*)d_ws;
    const size_t MB = 1024 * 1024;
    float*    M     = (float*)(ws + 0 * MB);            // 1 MB
    float*    Wov   = (float*)(ws + 1 * MB);            // 1 MB
    ushort_t* BsM   = (ushort_t*)(ws + 2 * MB);         // 1 MB   [512x1024] hi|lo
    ushort_t* BsW   = (ushort_t*)(ws + 3 * MB);         // 1 MB
    float*    bp    = (float*)(ws + 4 * MB);            // 2 KB
    float*    mc    = (float*)(ws + 4 * MB + 65536);    // 128 KB
    float*    wts   = (float*)(ws + 4 * MB + 262144);   // 256 B
    int*      dly   = (int*)(ws + 4 * MB + 266240);     // 256 B
    float2*   partial = (float2*)(ws + 5 * MB);         // 16 MB  [5,21)
    float*    XT    = (float*)(ws + 21 * MB);           // 64 MB  [21,85); reused as Xagg
    float*    YT    = (float*)(ws + 85 * MB);           // 64 MB  [85,149)
    float*    Xagg  = XT;

    // 1) M = Wq^T Wk ; Wov = Wo @ Wv ; bp = Wo@bv + bo ; bf16-split B matrices
    k_smallgemm<<<dim3(32, 32), dim3(16, 16), 0, stream>>>(Wq, Wk, M, ND, 1, ND, 1);
    k_smallgemm<<<dim3(32, 32), dim3(16, 16), 0, stream>>>(Wo, Wv, Wov, 1, ND, ND, 1);
    k_biasprep<<<1, 512, 0, stream>>>(Wo, bv, bo, bp);
    k_splitB<<<256, 256, 0, stream>>>(M, BsM);
    k_splitB<<<256, 256, 0, stream>>>(Wov, BsW);

    // 2) XT = transpose(X);  YT = (X @ M^T)^T  (split-bf16 MFMA)
    k_transpose<<<dim3(128, 16, NB), dim3(32, 8), 0, stream>>>(X, XT);
    k_gemm_split<0><<<dim3(256, 4), 256, 0, stream>>>(X, BsM, nullptr, YT);

    // 3) packed FFTs + channel-summed cross-spectrum; reduce + IFFT
    k_fft_fwd<<<512, 256, 0, stream>>>(XT, YT, partial);
    k_ifft<<<NB, 256, 0, stream>>>(partial, mc);

    // 4) top-8 delays + softmax weights
    k_topk<<<NB, 256, 0, stream>>>(mc, wts, dly);

    // 5) weighted circular gather
    k_gather<<<16384, 256, 0, stream>>>(X, wts, dly, Xagg);

    // 6) Out = Xagg @ Wov^T + bp  (split-bf16 MFMA)
    k_gemm_split<1><<<dim3(256, 4), 256, 0, stream>>>(Xagg, BsW, bp, Out);
}

// Round 3
// 612.430 us; speedup vs baseline: 1.8471x; 1.3375x over previous
//
#include <hip/hip_runtime.h>
#include <math.h>

// Problem constants (B=8, L=4096, D=512, H=8, top_k = int(log(4096)) = 8)
#define NB 8
#define NL 4096
#define ND 512
#define NK 8

typedef unsigned short ushort_t;
typedef __bf16 bf16x8 __attribute__((ext_vector_type(8)));
typedef float f32x4 __attribute__((ext_vector_type(4)));

__device__ __forceinline__ unsigned short f2bf(float x) {
    unsigned u = __builtin_bit_cast(unsigned, x);
    u += 0x7fff + ((u >> 16) & 1);   // round-to-nearest-even
    return (unsigned short)(u >> 16);
}
__device__ __forceinline__ float bf2f(unsigned short b) {
    unsigned u = ((unsigned)b) << 16;
    return __builtin_bit_cast(float, u);
}

// ---------------------------------------------------------------------------
// Small GEMM: C[i,j] = sum_{k<512} A[k*sa_k + i*sa_i] * B[k*sb_k + j*sb_j]
// ---------------------------------------------------------------------------
__global__ void k_smallgemm(const float* __restrict__ A, const float* __restrict__ Bm,
                            float* __restrict__ C, int sa_k, int sa_i, int sb_k, int sb_j) {
    int i = blockIdx.y * 16 + threadIdx.y;
    int j = blockIdx.x * 16 + threadIdx.x;
    float acc = 0.f;
    for (int k = 0; k < ND; ++k)
        acc += A[k * sa_k + i * sa_i] * Bm[k * sb_k + j * sb_j];
    C[i * ND + j] = acc;
}

// bp[i] = bo[i] + sum_k Wo[i,k]*bv[k]
__global__ void k_biasprep(const float* __restrict__ Wo, const float* __restrict__ bv,
                           const float* __restrict__ bo, float* __restrict__ bp) {
    int i = blockIdx.x * blockDim.x + threadIdx.x;
    float acc = bo[i];
    for (int k = 0; k < ND; ++k) acc += Wo[i * ND + k] * bv[k];
    bp[i] = acc;
}

// Split fp32 rows into [row][0:512]=hi bf16, [row][512:1024]=lo bf16.
// grid = rows/2 blocks of 256 threads (each thread: 4 elements).
__global__ __launch_bounds__(256) void k_split(const float* __restrict__ src,
                                               ushort_t* __restrict__ dst) {
    int gid = blockIdx.x * 256 + threadIdx.x;
    int row = gid >> 7;
    int kc = (gid & 127) * 4;
    float4 v = *(const float4*)(src + (size_t)row * ND + kc);
    ushort4 hi, lo;
    hi.x = f2bf(v.x); lo.x = f2bf(v.x - bf2f(hi.x));
    hi.y = f2bf(v.y); lo.y = f2bf(v.y - bf2f(hi.y));
    hi.z = f2bf(v.z); lo.z = f2bf(v.z - bf2f(hi.z));
    hi.w = f2bf(v.w); lo.w = f2bf(v.w - bf2f(hi.w));
    *(ushort4*)(dst + (size_t)row * 1024 + kc) = hi;
    *(ushort4*)(dst + (size_t)row * 1024 + 512 + kc) = lo;
}

// ---------------------------------------------------------------------------
// Transpose X[b,l,c] -> XT[b,c,l]   (32x32 LDS tiles)
// ---------------------------------------------------------------------------
__global__ __launch_bounds__(256) void k_transpose(const float* __restrict__ X,
                                                   float* __restrict__ XT) {
    __shared__ float t[32][33];
    int b  = blockIdx.z;
    int l0 = blockIdx.x * 32;
    int c0 = blockIdx.y * 32;
    const float* Xb = X + (size_t)b * NL * ND;
    float* XTb = XT + (size_t)b * ND * NL;
    int tx = threadIdx.x, ty = threadIdx.y;  // 32 x 8
#pragma unroll
    for (int j = 0; j < 4; ++j)
        t[ty + j * 8][tx] = Xb[(size_t)(l0 + ty + j * 8) * ND + c0 + tx];
    __syncthreads();
#pragma unroll
    for (int j = 0; j < 4; ++j)
        XTb[(size_t)(c0 + ty + j * 8) * NL + l0 + tx] = t[tx][ty + j * 8];
}

// ---------------------------------------------------------------------------
// Split-bf16 MFMA GEMM:  C[r,n] = sum_k A[r,k] * Brow[n,k]
// A, B both pre-split bf16 [rows][1024] = hi(512) | lo(512); staged to LDS via
// global_load_lds width=16 with XOR chunk swizzle (c' = c ^ ((row>>1)&3)) so
// fragment ds_read_b128 are bank-conflict-free.
// 3-term split: Ah*Bh + Ah*Bl + Al*Bh.
// 128x128 C-tile, 256 thr = 4 waves (2x2), 4x4 16x16x32 MFMA frags per wave.
// EPI=0: write transposed YT[b,n,l]; EPI=1: bias + plain [r,n].
// ---------------------------------------------------------------------------
template <int EPI>
__global__ __launch_bounds__(256) void k_gemm_split(const ushort_t* __restrict__ As,
                                                    const ushort_t* __restrict__ Bs,
                                                    const float* __restrict__ bp,
                                                    float* __restrict__ Out) {
    __shared__ union USm {
        struct { ushort_t ahi[128 * 32]; ushort_t alo[128 * 32];
                 ushort_t bhi[128 * 32]; ushort_t blo[128 * 32]; } s;  // 32 KB
        float t[32 * 132];                                             // epilogue transpose
    } sm;
    const int tid = threadIdx.x;
    const int l0 = blockIdx.x * 128;
    const int n0 = blockIdx.y * 128;
    const int lane = tid & 63;
    const int w = tid >> 6;
    const int wr = (w & 1) * 64;
    const int wc = (w >> 1) * 64;
    const int m = lane & 15;
    const int quad = lane >> 4;

    f32x4 acc[4][4];
#pragma unroll
    for (int i = 0; i < 4; ++i)
#pragma unroll
        for (int j = 0; j < 4; ++j) acc[i][j] = (f32x4){0.f, 0.f, 0.f, 0.f};

    for (int k0 = 0; k0 < ND; k0 += 32) {
        __syncthreads();   // prior iteration's fragment reads complete
#pragma unroll
        for (int v = 0; v < 2; ++v) {
            int q = v * 256 + tid;            // 16B chunk id within 128x32 tile
            int r = q >> 2;                   // tile row
            int c = (q & 3) ^ ((r >> 1) & 3); // swizzled source chunk
            const ushort_t* asrc = As + (size_t)(l0 + r) * 1024 + k0 + c * 8;
            __builtin_amdgcn_global_load_lds(
                (const __attribute__((address_space(1))) unsigned int*)asrc,
                (__attribute__((address_space(3))) unsigned int*)&sm.s.ahi[q * 8], 16, 0, 0);
            __builtin_amdgcn_global_load_lds(
                (const __attribute__((address_space(1))) unsigned int*)(asrc + 512),
                (__attribute__((address_space(3))) unsigned int*)&sm.s.alo[q * 8], 16, 0, 0);
            const ushort_t* bsrc = Bs + (size_t)(n0 + r) * 1024 + k0 + c * 8;
            __builtin_amdgcn_global_load_lds(
                (const __attribute__((address_space(1))) unsigned int*)bsrc,
                (__attribute__((address_space(3))) unsigned int*)&sm.s.bhi[q * 8], 16, 0, 0);
            __builtin_amdgcn_global_load_lds(
                (const __attribute__((address_space(1))) unsigned int*)(bsrc + 512),
                (__attribute__((address_space(3))) unsigned int*)&sm.s.blo[q * 8], 16, 0, 0);
        }
        __syncthreads();   // waits vmcnt(0): DMA landed

        bf16x8 ah[4], al[4];
#pragma unroll
        for (int i = 0; i < 4; ++i) {
            int row = wr + 16 * i + m;
            int off = row * 32 + ((quad ^ ((row >> 1) & 3)) * 8);
            ah[i] = *(const bf16x8*)&sm.s.ahi[off];
            al[i] = *(const bf16x8*)&sm.s.alo[off];
        }
#pragma unroll
        for (int j = 0; j < 4; ++j) {
            int row = wc + 16 * j + m;
            int off = row * 32 + ((quad ^ ((row >> 1) & 3)) * 8);
            bf16x8 bh = *(const bf16x8*)&sm.s.bhi[off];
            bf16x8 bl = *(const bf16x8*)&sm.s.blo[off];
#pragma unroll
            for (int i = 0; i < 4; ++i) {
                acc[i][j] = __builtin_amdgcn_mfma_f32_16x16x32_bf16(ah[i], bh, acc[i][j], 0, 0, 0);
                acc[i][j] = __builtin_amdgcn_mfma_f32_16x16x32_bf16(ah[i], bl, acc[i][j], 0, 0, 0);
                acc[i][j] = __builtin_amdgcn_mfma_f32_16x16x32_bf16(al[i], bh, acc[i][j], 0, 0, 0);
            }
        }
    }

    if (EPI == 1) {
        // bias + plain [row, col]
#pragma unroll
        for (int j = 0; j < 4; ++j) {
            int col = n0 + wc + 16 * j + m;
            float bv = bp[col];
#pragma unroll
            for (int i = 0; i < 4; ++i) {
                size_t rbase = (size_t)(l0 + wr + 16 * i + quad * 4) * ND + col;
#pragma unroll
                for (int r = 0; r < 4; ++r)
                    Out[rbase + (size_t)r * ND] = acc[i][j][r] + bv;
            }
        }
    } else {
        // transposed write YT[b, n, l] via LDS, 32-col chunks
#pragma unroll
        for (int c = 0; c < 4; ++c) {
            __syncthreads();
            if ((wc >> 6) == (c >> 1)) {
                int jb = (c & 1) * 2;
#pragma unroll
                for (int jj = 0; jj < 2; ++jj) {
                    int j = jb + jj;
                    int cl = 16 * jj + m;
#pragma unroll
                    for (int i = 0; i < 4; ++i)
#pragma unroll
                        for (int r = 0; r < 4; ++r)
                            sm.t[cl * 132 + wr + 16 * i + quad * 4 + r] = acc[i][j][r];
                }
            }
            __syncthreads();
#pragma unroll
            for (int it = 0; it < 16; ++it) {
                int idx = it * 256 + tid;
                int cl = idx >> 7;
                int row = idx & 127;
                int rg = l0 + row;
                Out[((size_t)((rg >> 12) * ND + n0 + c * 32 + cl)) * NL + (rg & 4095)] =
                    sm.t[cl * 132 + row];
            }
        }
    }
}

// ---------------------------------------------------------------------------
// 16-point in-register DFT (natural in/out). DIR=+1 fwd (e^{-i}), -1 inverse.
// ---------------------------------------------------------------------------
template <int DIR>
__device__ __forceinline__ void fft16(float2* v) {
    const float ct[8] = {1.f, 0.923879533f, 0.707106781f, 0.382683432f,
                         0.f, -0.382683432f, -0.707106781f, -0.923879533f};
    const float st[8] = {0.f, 0.382683432f, 0.707106781f, 0.923879533f,
                         1.f, 0.923879533f, 0.707106781f, 0.382683432f};
    const int br[16] = {0, 8, 4, 12, 2, 10, 6, 14, 1, 9, 5, 13, 3, 11, 7, 15};
    float2 a[16];
#pragma unroll
    for (int i = 0; i < 16; ++i) a[i] = v[br[i]];
#pragma unroll
    for (int s = 1; s <= 4; ++s) {
        const int L = 1 << s, h = L >> 1;
#pragma unroll
        for (int g = 0; g < 16; g += L)
#pragma unroll
            for (int p = 0; p < h; ++p) {
                int k = p << (4 - s);
                float wr = ct[k];
                float wi = (DIR > 0) ? -st[k] : st[k];
                int i1 = g + p, i2 = i1 + h;
                float tr = wr * a[i2].x - wi * a[i2].y;
                float ti = wr * a[i2].y + wi * a[i2].x;
                a[i2].x = a[i1].x - tr; a[i2].y = a[i1].y - ti;
                a[i1].x += tr;          a[i1].y += ti;
            }
    }
#pragma unroll
    for (int i = 0; i < 16; ++i) v[i] = a[i];
}

__device__ __forceinline__ float2 cmul(float2 a, float2 b) {
    return make_float2(a.x * b.x - a.y * b.y, a.x * b.y + a.y * b.x);
}
#define PADI(i) ((i) + ((i) >> 4))

// ---------------------------------------------------------------------------
// Forward: per (batch, group of 8 channels): z = x + i*y, 4096-pt Stockham
// radix-16 FFT (3 stages), accumulate cross-spectrum
// X_c(f)*conj(Y_c(f)) = Im(Z_f*Z_{-f})/2 + i*(|Z_f|^2-|Z_{-f}|^2)/4
// into partial[b, g, f].
// ---------------------------------------------------------------------------
__global__ __launch_bounds__(256) void k_fft_fwd(const float* __restrict__ XT,
                                                 const float* __restrict__ YT,
                                                 float2* __restrict__ partial) {
    __shared__ float2 data[4352];   // 4096 + pad
    const int t = threadIdx.x;
    const int b = blockIdx.x >> 6;
    const int g = blockIdx.x & 63;

    float sv, cv;
    sincosf(-6.283185307179586f * (float)(t & 15) / 256.0f, &sv, &cv);
    const float2 w2 = make_float2(cv, sv);
    sincosf(-6.283185307179586f * (float)t / 4096.0f, &sv, &cv);
    const float2 w3 = make_float2(cv, sv);

    float2 acc[16];
#pragma unroll
    for (int r = 0; r < 16; ++r) acc[r] = make_float2(0.f, 0.f);

    for (int ch = 0; ch < 8; ++ch) {
        int c = g * 8 + ch;
        const float* xr = XT + ((size_t)b * ND + c) * NL;
        const float* yr = YT + ((size_t)b * ND + c) * NL;
        float2 v[16];
        // stage 1 (Ns=1): read natural, fft16, write idx 16t+m
#pragma unroll
        for (int mm = 0; mm < 16; ++mm)
            v[mm] = make_float2(xr[t + 256 * mm], yr[t + 256 * mm]);
        fft16<1>(v);
        __syncthreads();   // prior channel's pair-reads done
#pragma unroll
        for (int mm = 0; mm < 16; ++mm) data[PADI(16 * t + mm)] = v[mm];
        __syncthreads();
        // stage 2 (Ns=16)
#pragma unroll
        for (int mm = 0; mm < 16; ++mm) v[mm] = data[PADI(t + 256 * mm)];
        {
            float2 wm = make_float2(1.f, 0.f);
#pragma unroll
            for (int mm = 1; mm < 16; ++mm) { wm = cmul(wm, w2); v[mm] = cmul(v[mm], wm); }
        }
        fft16<1>(v);
        __syncthreads();
        {
            int base = (t >> 4) * 256 + (t & 15);
#pragma unroll
            for (int mm = 0; mm < 16; ++mm) data[PADI(base + 16 * mm)] = v[mm];
        }
        __syncthreads();
        // stage 3 (Ns=256) -> natural-order Z in registers
#pragma unroll
        for (int mm = 0; mm < 16; ++mm) v[mm] = data[PADI(t + 256 * mm)];
        {
            float2 wm = make_float2(1.f, 0.f);
#pragma unroll
            for (int mm = 1; mm < 16; ++mm) { wm = cmul(wm, w3); v[mm] = cmul(v[mm], wm); }
        }
        fft16<1>(v);
        __syncthreads();
#pragma unroll
        for (int mm = 0; mm < 16; ++mm) data[PADI(t + 256 * mm)] = v[mm];
        __syncthreads();
        // cross-spectrum accumulate
#pragma unroll
        for (int mm = 0; mm < 16; ++mm) {
            int f = t + 256 * mm;
            float2 A = v[mm];
            float2 Bz = data[PADI((4096 - f) & 4095)];
            acc[mm].x += 0.5f * (A.x * Bz.y + A.y * Bz.x);
            acc[mm].y += 0.25f * ((A.x * A.x + A.y * A.y) - (Bz.x * Bz.x + Bz.y * Bz.y));
        }
    }
    float2* out = partial + ((size_t)b * 64 + g) * 4096;
#pragma unroll
    for (int mm = 0; mm < 16; ++mm) out[256 * mm + t] = acc[mm];
}

// Reduce 64 partials -> Cf[b][f]
__global__ __launch_bounds__(256) void k_reduce(const float2* __restrict__ partial,
                                                float2* __restrict__ Cf) {
    int b = blockIdx.x >> 4;
    int f = (blockIdx.x & 15) * 256 + threadIdx.x;
    float2 s = make_float2(0.f, 0.f);
    for (int g = 0; g < 64; ++g) {
        float2 v = partial[((size_t)(b * 64 + g)) * 4096 + f];
        s.x += v.x; s.y += v.y;
    }
    Cf[(size_t)b * 4096 + f] = s;
}

// Inverse 4096-pt Stockham on Cf -> mean_corr (real part, scaled)
__global__ __launch_bounds__(256) void k_ifft(const float2* __restrict__ Cf,
                                              float* __restrict__ mc) {
    __shared__ float2 data[4352];
    const int t = threadIdx.x;
    const int b = blockIdx.x;
    float sv, cv;
    sincosf(6.283185307179586f * (float)(t & 15) / 256.0f, &sv, &cv);
    const float2 w2 = make_float2(cv, sv);
    sincosf(6.283185307179586f * (float)t / 4096.0f, &sv, &cv);
    const float2 w3 = make_float2(cv, sv);

    float2 v[16];
#pragma unroll
    for (int mm = 0; mm < 16; ++mm) v[mm] = Cf[(size_t)b * 4096 + t + 256 * mm];
    fft16<-1>(v);
#pragma unroll
    for (int mm = 0; mm < 16; ++mm) data[PADI(16 * t + mm)] = v[mm];
    __syncthreads();
#pragma unroll
    for (int mm = 0; mm < 16; ++mm) v[mm] = data[PADI(t + 256 * mm)];
    {
        float2 wm = make_float2(1.f, 0.f);
#pragma unroll
        for (int mm = 1; mm < 16; ++mm) { wm = cmul(wm, w2); v[mm] = cmul(v[mm], wm); }
    }
    fft16<-1>(v);
    __syncthreads();
    {
        int base = (t >> 4) * 256 + (t & 15);
#pragma unroll
        for (int mm = 0; mm < 16; ++mm) data[PADI(base + 16 * mm)] = v[mm];
    }
    __syncthreads();
#pragma unroll
    for (int mm = 0; mm < 16; ++mm) v[mm] = data[PADI(t + 256 * mm)];
    {
        float2 wm = make_float2(1.f, 0.f);
#pragma unroll
        for (int mm = 1; mm < 16; ++mm) { wm = cmul(wm, w3); v[mm] = cmul(v[mm], wm); }
    }
    fft16<-1>(v);
    const float scale = 1.0f / (4096.0f * 512.0f);
#pragma unroll
    for (int mm = 0; mm < 16; ++mm)
        mc[(size_t)b * NL + t + 256 * mm] = v[mm].x * scale;
}

// ---------------------------------------------------------------------------
// Top-8 + softmax per batch
// ---------------------------------------------------------------------------
__global__ __launch_bounds__(256) void k_topk(const float* __restrict__ mc,
                                              float* __restrict__ wts,
                                              int* __restrict__ dly) {
    __shared__ float vals[4096];
    __shared__ float rv[256];
    __shared__ int ri[256];
    __shared__ float tv[NK];
    __shared__ int tix[NK];
    const int tid = threadIdx.x;
    const int b = blockIdx.x;
    for (int t = tid; t < 4096; t += 256) vals[t] = mc[(size_t)b * NL + t];
    __syncthreads();
    for (int it = 0; it < NK; ++it) {
        float bv = -3.0e38f;
        int bi = 0;
        for (int t = tid; t < 4096; t += 256) {
            float v = vals[t];
            if (v > bv) { bv = v; bi = t; }
        }
        rv[tid] = bv;
        ri[tid] = bi;
        __syncthreads();
        for (int off = 128; off > 0; off >>= 1) {
            if (tid < off) {
                if (rv[tid + off] > rv[tid]) {
                    rv[tid] = rv[tid + off];
                    ri[tid] = ri[tid + off];
                }
            }
            __syncthreads();
        }
        if (tid == 0) {
            tv[it] = rv[0];
            tix[it] = ri[0];
            vals[ri[0]] = -3.0e38f;
        }
        __syncthreads();
    }
    if (tid == 0) {
        float mx = tv[0];
        float e[NK], s = 0.f;
        for (int i = 0; i < NK; ++i) { e[i] = expf(tv[i] - mx); s += e[i]; }
        for (int i = 0; i < NK; ++i) {
            wts[b * NK + i] = e[i] / s;
            dly[b * NK + i] = tix[i];
        }
    }
}

// ---------------------------------------------------------------------------
// Xagg[b,l,:] = sum_i w[b,i] * X[b,(l+d_i)%L,:], written split bf16 hi|lo
// ---------------------------------------------------------------------------
__global__ __launch_bounds__(256) void k_gather(const float* __restrict__ X,
                                                const float* __restrict__ wts,
                                                const int* __restrict__ dly,
                                                ushort_t* __restrict__ Xaggs) {
    __shared__ float sw[NK];
    __shared__ int sd[NK];
    int gid = blockIdx.x * 256 + threadIdx.x;
    int b = gid >> 19;
    int rem = gid & 524287;
    int l = rem >> 7;
    int c4 = rem & 127;
    if (threadIdx.x < NK) {
        sw[threadIdx.x] = wts[b * NK + threadIdx.x];
        sd[threadIdx.x] = dly[b * NK + threadIdx.x];
    }
    __syncthreads();
    const float4* Xb = (const float4*)X + (size_t)b * 524288;
    float4 s = make_float4(0.f, 0.f, 0.f, 0.f);
#pragma unroll
    for (int i = 0; i < NK; ++i) {
        int ls = (l + sd[i]) & (NL - 1);
        float4 v = Xb[(size_t)ls * 128 + c4];
        float w = sw[i];
        s.x += w * v.x;
        s.y += w * v.y;
        s.z += w * v.z;
        s.w += w * v.w;
    }
    ushort4 hi, lo;
    hi.x = f2bf(s.x); lo.x = f2bf(s.x - bf2f(hi.x));
    hi.y = f2bf(s.y); lo.y = f2bf(s.y - bf2f(hi.y));
    hi.z = f2bf(s.z); lo.z = f2bf(s.z - bf2f(hi.z));
    hi.w = f2bf(s.w); lo.w = f2bf(s.w - bf2f(hi.w));
    ushort_t* rowp = Xaggs + (size_t)(b * NL + l) * 1024;
    *(ushort4*)(rowp + c4 * 4) = hi;
    *(ushort4*)(rowp + 512 + c4 * 4) = lo;
}

// ---------------------------------------------------------------------------
extern "C" void kernel_launch(void* const* d_in, const int* in_sizes, int n_in,
                              void* d_out, int out_size, void* d_ws, size_t ws_size,
                              hipStream_t stream) {
    (void)in_sizes; (void)n_in; (void)out_size; (void)ws_size;
    const float* X  = (const float*)d_in[0];
    const float* Wq = (const float*)d_in[1];
    const float* Wk = (const float*)d_in[3];
    const float* Wv = (const float*)d_in[5];
    const float* bv = (const float*)d_in[6];
    const float* Wo = (const float*)d_in[7];
    const float* bo = (const float*)d_in[8];
    float* Out = (float*)d_out;

    char* ws = (char*)d_ws;
    const size_t MB = 1024 * 1024;
    // misc [0,5) MiB
    float*    M     = (float*)(ws + 0 * MB);             // 1 MB
    float*    Wov   = (float*)(ws + 1 * MB);             // 1 MB
    ushort_t* BsM   = (ushort_t*)(ws + 2 * MB);          // 1 MB
    ushort_t* BsW   = (ushort_t*)(ws + 3 * MB);          // 1 MB
    float*    bp    = (float*)(ws + 4 * MB);             // 2 KB
    float*    mc    = (float*)(ws + 4 * MB + 0x10000);   // 128 KB
    float*    wts   = (float*)(ws + 4 * MB + 0x40000);   // 256 B
    int*      dly   = (int*)(ws + 4 * MB + 0x41000);     // 256 B
    float2*   Cf    = (float2*)(ws + 4 * MB + 0x80000);  // 256 KB
    // partial [5,21) MiB (16 MiB exact)
    float2*   partial = (float2*)(ws + 5 * MB);
    // R0 [21,85): Xs (split X) -> XT (fp32 transpose) -> (unused)
    ushort_t* Xs    = (ushort_t*)(ws + 21 * MB);
    float*    XT    = (float*)(ws + 21 * MB);
    // R1 [85,149): YT -> Xaggs (YT dead after fft_fwd)
    float*    YT    = (float*)(ws + 85 * MB);
    ushort_t* Xaggs = (ushort_t*)(ws + 85 * MB);

    // 1) weight prep: M = Wq^T Wk ; Wov = Wo @ Wv ; bp ; bf16 splits
    k_smallgemm<<<dim3(32, 32), dim3(16, 16), 0, stream>>>(Wq, Wk, M, ND, 1, ND, 1);
    k_smallgemm<<<dim3(32, 32), dim3(16, 16), 0, stream>>>(Wo, Wv, Wov, 1, ND, ND, 1);
    k_biasprep<<<1, 512, 0, stream>>>(Wo, bv, bo, bp);
    k_split<<<256, 256, 0, stream>>>(M, BsM);
    k_split<<<256, 256, 0, stream>>>(Wov, BsW);

    // 2) Xs = split(X);  YT = (X @ M^T)^T  (MFMA, DMA-staged, swizzled LDS)
    k_split<<<16384, 256, 0, stream>>>(X, Xs);
    k_gemm_split<0><<<dim3(256, 4), 256, 0, stream>>>(Xs, BsM, nullptr, YT);

    // 3) XT = transpose(X)  (overwrites Xs region - Xs dead after GEMM1)
    k_transpose<<<dim3(128, 16, NB), dim3(32, 8), 0, stream>>>(X, XT);

    // 4) packed Stockham FFTs + channel-summed cross-spectrum; reduce; IFFT
    k_fft_fwd<<<512, 256, 0, stream>>>(XT, YT, partial);
    k_reduce<<<128, 256, 0, stream>>>(partial, Cf);
    k_ifft<<<NB, 256, 0, stream>>>(Cf, mc);

    // 5) top-8 delays + softmax weights
    k_topk<<<NB, 256, 0, stream>>>(mc, wts, dly);

    // 6) weighted circular gather, split-bf16 output (YT region, dead)
    k_gather<<<16384, 256, 0, stream>>>(X, wts, dly, Xaggs);

    // 7) Out = Xagg @ Wov^T + bp  (MFMA)
    k_gemm_split<1><<<dim3(256, 4), 256, 0, stream>>>(Xaggs, BsW, bp, Out);
}